// Round 3
// baseline (370.891 us; speedup 1.0000x reference)
//
#include <hip/hip_runtime.h>
#include <hip/hip_bf16.h>

#define N_NODES 100000
#define NP1 (N_NODES + 1)
#define N_EDGES 3200000
#define NB ((N_NODES + 255) / 256)   // 391
#define NBUCKET NB                   // coarse bucket = dst>>8
#define EPB 8192                     // edges per k_pass1 block
#define NPB ((N_EDGES + EPB - 1) / EPB)  // 391 blocks
#define BCAP 11264                   // per-bucket cap incl self+pad(8)+guard; mean ~9344, 20 sigma
#define KF_BLOCKS 1280               // k_final: 5120 waves = 5 waves/SIMD
#define KF_WAVES (KF_BLOCKS * 4)
#define PBLK 6250                    // k_agg blocks per plane: 16 nodes/block * 6250 = 100000

// clang-native vector types (HIP's uint4/float4 are structs and are rejected
// by __builtin_nontemporal_*)
typedef unsigned int uint4v __attribute__((ext_vector_type(4)));
typedef float float4v __attribute__((ext_vector_type(4)));

// RNE float->bf16 bits (matches __float2bfloat16 for finite values)
__device__ inline unsigned f2bf(float f) {
  unsigned x = __float_as_uint(f);
  return (x + 0x7FFFu + ((x >> 16) & 1u)) >> 16;
}

// ---------------- pass 1: register-resident coarse partition ----------------
// item: bits[16:0] = src, bits[24:17] = dst & 255 (bucket = dst>>8).
// Single LDS-atomic round: per-item position packed into bits[31:25].

__global__ void __launch_bounds__(256) k_pass1(const int* __restrict__ src,
                                               const int* __restrict__ dst,
                                               int* __restrict__ gcur,
                                               unsigned int* __restrict__ eb) {
  __shared__ int hist[NBUCKET];
  __shared__ int gbase[NBUCKET];
  int tid = threadIdx.x;
  int base = blockIdx.x * EPB;
  int cnt = min(EPB, N_EDGES - base);   // multiple of 4
  int n4 = cnt >> 2;
  for (int i = tid; i < NBUCKET; i += 256) hist[i] = 0;
  __syncthreads();
  const int4* d4 = (const int4*)(dst + base);
  const int4* s4 = (const int4*)(src + base);
  unsigned mv[32];
  unsigned short mb[32];
#pragma unroll
  for (int k = 0; k < 8; ++k) {
    int i = tid + (k << 8);
    if (i < n4) {
      int4 dv = d4[i];
      int4 sv = s4[i];
      int b0 = dv.x >> 8, b1_ = dv.y >> 8, b2 = dv.z >> 8, b3 = dv.w >> 8;
      unsigned p0 = atomicAdd(&hist[b0], 1);
      unsigned p1 = atomicAdd(&hist[b1_], 1);
      unsigned p2 = atomicAdd(&hist[b2], 1);
      unsigned p3 = atomicAdd(&hist[b3], 1);
      mv[4 * k + 0] = (unsigned)sv.x | ((unsigned)(dv.x & 255) << 17) | (p0 << 25);
      mv[4 * k + 1] = (unsigned)sv.y | ((unsigned)(dv.y & 255) << 17) | (p1 << 25);
      mv[4 * k + 2] = (unsigned)sv.z | ((unsigned)(dv.z & 255) << 17) | (p2 << 25);
      mv[4 * k + 3] = (unsigned)sv.w | ((unsigned)(dv.w & 255) << 17) | (p3 << 25);
      mb[4 * k + 0] = (unsigned short)b0;
      mb[4 * k + 1] = (unsigned short)b1_;
      mb[4 * k + 2] = (unsigned short)b2;
      mb[4 * k + 3] = (unsigned short)b3;
    } else {
      mb[4 * k + 0] = 0xFFFF; mb[4 * k + 1] = 0xFFFF;
      mb[4 * k + 2] = 0xFFFF; mb[4 * k + 3] = 0xFFFF;
    }
  }
  __syncthreads();
  for (int b = tid; b < NBUCKET; b += 256) {
    int h = hist[b];
    gbase[b] = h ? atomicAdd(&gcur[b], h) : 0;   // one claim per (block,bucket)
  }
  __syncthreads();
#pragma unroll
  for (int k = 0; k < 32; ++k) {
    if (mb[k] != 0xFFFF) {
      int b = mb[k];
      unsigned v = mv[k];
      unsigned pos = (unsigned)gbase[b] + (v >> 25);
      if (pos < BCAP) eb[(size_t)b * BCAP + pos] = v & 0x01FFFFFFu;
    }
  }
}

// ---------------- pass 2: per-bucket counting sort + self-edge + pad-to-8 --------
// Node n's run: [rs[n], re[n]) real (self first), pads == N_NODES to a multiple
// of 8, 16-entry guard after the bucket total. Also emits dis, xd = x4*dis.

__global__ void __launch_bounds__(256) k_part2(unsigned int* __restrict__ eb,
                                               const int* __restrict__ gcur,
                                               int* __restrict__ rs, int* __restrict__ re,
                                               float* __restrict__ dis,
                                               const float4* __restrict__ x4,
                                               float4* __restrict__ xd) {
  __shared__ int hist[256], scn[256], cur[256];
  __shared__ int tot;
  __shared__ unsigned int stage[BCAP];
  int b = blockIdx.x, tid = threadIdx.x;
  int n0 = b << 8;
  int cnt = gcur[b];
  int base = b * BCAP;
  hist[tid] = 0; cur[tid] = 0;
  __syncthreads();
  for (int i = tid; i < cnt; i += 256)
    atomicAdd(&hist[eb[base + i] >> 17], 1);
  __syncthreads();
  int n = n0 + tid;
  int deg = hist[tid];
  int slots = (n < N_NODES) ? ((deg + 1 + 7) & ~7) : 0;
  int x = slots;
  scn[tid] = x;
  __syncthreads();
  for (int off = 1; off < 256; off <<= 1) {
    int t = (tid >= off) ? scn[tid - off] : 0;
    __syncthreads();
    x += t; scn[tid] = x;
    __syncthreads();
  }
  int excl = x - slots;
  if (tid == 255) tot = x;
  if (n < N_NODES) {
    rs[n]  = base + excl;
    re[n]  = base + excl + deg + 1;
    float dn = rsqrtf((float)(deg + 1));
    dis[n] = dn;
    float4 xv = x4[n];
    float4 w; w.x = xv.x * dn; w.y = xv.y * dn; w.z = xv.z * dn; w.w = xv.w * dn;
    xd[n] = w;
    stage[excl] = (unsigned)n;                    // self edge
    for (int i = deg + 1; i < slots; ++i)
      stage[excl + i] = (unsigned)N_NODES;        // zero-row pads
  }
  if (b == 0 && tid == 0) xd[N_NODES] = make_float4(0.f, 0.f, 0.f, 0.f);
  scn[tid] = excl + 1;                            // in-edge start
  __syncthreads();
  for (int i = tid; i < cnt; i += 256) {
    unsigned v = eb[base + i];
    unsigned low = v >> 17;
    int lpos = scn[low] + atomicAdd(&cur[low], 1);
    stage[lpos] = v & 0x1FFFFu;
  }
  __syncthreads();
  int total = tot;
  for (int i = tid; i < total; i += 256)
    eb[base + i] = stage[i];     // eb is now padded CSR (src ids by dst node)
  if (tid < 16) {                // guard pads (k_agg predicates its over-reads,
    int gp = total + tid;        //  but keep guards so discarded loads see N_NODES)
    if (gp < BCAP) eb[base + gp] = (unsigned)N_NODES;
  }
}

// ---------------- Layer 1 fused: aggregate xd + transform + bf16 store ----------
// 4 threads per node (p = gt&3). Thread p reads csr dwords e0+4t+p (slots are
// multiples of 8; pads hit xd's zero row), shfl_xor combine, then writes
// PLANE p (features [16p,16p+16)) of the plane-major bf16 h1 buffer:
// h1q[p][n][16] = bf16(relu(b1 + agg·W1) * dis[n]). Each plane is 3.2 MB so
// k_agg's gathers become per-XCD-L2-resident.

__global__ void __launch_bounds__(256) k_l1(const float4* __restrict__ xd,
                                            const float* __restrict__ dis,
                                            const int* __restrict__ rs,
                                            const int* __restrict__ re,
                                            const int* __restrict__ csr,
                                            const float* __restrict__ W1,
                                            const float* __restrict__ b1,
                                            unsigned int* __restrict__ h1o) {
  int gt = blockIdx.x * 256 + threadIdx.x;
  int nid = gt >> 2, p = gt & 3;
  if (nid > N_NODES) return;
  unsigned int* op32 = h1o + ((size_t)p * NP1 + nid) * 8;
  if (nid == N_NODES) {                       // zero row (pad target for k_agg)
    uint4v z = (uint4v)(0u);
    __builtin_nontemporal_store(z, (uint4v*)op32);
    __builtin_nontemporal_store(z, (uint4v*)op32 + 1);
    return;
  }
  int e0 = rs[nid];
  int it4 = ((re[nid] - e0 + 7) & ~7) >> 2;   // dword quads per thread-pass
  const int* cp = csr + e0 + p;
  float ax = 0.f, ay = 0.f, az = 0.f, aw = 0.f;
#pragma unroll 4
  for (int t = 0; t < it4; ++t) {
    int s = __builtin_nontemporal_load(cp + (t << 2));
    float4 v = xd[s];
    ax += v.x; ay += v.y; az += v.z; aw += v.w;
  }
  ax += __shfl_xor(ax, 1); ax += __shfl_xor(ax, 2);
  ay += __shfl_xor(ay, 1); ay += __shfl_xor(ay, 2);
  az += __shfl_xor(az, 1); az += __shfl_xor(az, 2);
  aw += __shfl_xor(aw, 1); aw += __shfl_xor(aw, 2);
  float dn = dis[nid];
  ax *= dn; ay *= dn; az *= dn; aw *= dn;     // agg1[nid]
  int j0 = p << 4;
  unsigned ou[8];
#pragma unroll
  for (int j2 = 0; j2 < 8; ++j2) {
    int j = j0 + j2 * 2;
    float s0 = b1[j]     + ax * W1[j]     + ay * W1[64 + j]     + az * W1[128 + j]     + aw * W1[192 + j];
    float s1 = b1[j + 1] + ax * W1[j + 1] + ay * W1[64 + j + 1] + az * W1[128 + j + 1] + aw * W1[192 + j + 1];
    unsigned u0 = f2bf(fmaxf(s0, 0.f) * dn);
    unsigned u1 = f2bf(fmaxf(s1, 0.f) * dn);
    ou[j2] = u0 | (u1 << 16);
  }
  uint4v o0; o0.x = ou[0]; o0.y = ou[1]; o0.z = ou[2]; o0.w = ou[3];
  uint4v o1; o1.x = ou[4]; o1.y = ou[5]; o1.z = ou[6]; o1.w = ou[7];
  __builtin_nontemporal_store(o0, (uint4v*)op32);
  __builtin_nontemporal_store(o1, (uint4v*)op32 + 1);
}

// ---------------- Layer-2 aggregation: plane-split L2-resident gather ----------
// Plane-major grid: blockIdx = plane*PBLK + b, so in-flight blocks share ONE
// 3.2 MB feature plane (per-XCD-L2-resident). Wave per 4 nodes; lane l:
// g = l>>1 (32 edges in flight), c = l&1 (16-B chunk of the 32-B plane row).
// csr/rs/re/dis loads and agg stores are nontemporal so streams don't evict
// the plane. Over-reach beyond a node's padded run is predicated to the zero
// row BEFORE the gather (csr guard + workspace slack keeps raw reads in-bounds).

__device__ inline void acc_bf2(float& a0, float& a1, unsigned u) {
  a0 += __uint_as_float(u << 16);
  a1 += __uint_as_float(u & 0xffff0000u);
}

__global__ void __launch_bounds__(256)
k_agg(const unsigned int* __restrict__ h1q,  // [4][N+1][8] dwords
      const float* __restrict__ dis,
      const int* __restrict__ rs, const int* __restrict__ re,
      const int* __restrict__ csr, float* __restrict__ agg) {
  int l = threadIdx.x & 63;
  int w = threadIdx.x >> 6;
  int bid = blockIdx.x;
  int plane = bid / PBLK;
  int nb = bid - plane * PBLK;
  int g = l >> 1;                              // edge subgroup 0..31
  int coff = (l & 1) << 2;                     // dword offset of 16-B chunk
  const unsigned int* pb = h1q + (size_t)plane * NP1 * 8;
  int n0 = (nb * 4 + w) * 4;

#pragma unroll 1
  for (int j = 0; j < 4; ++j) {
    int n = n0 + j;
    int e0 = __builtin_nontemporal_load(rs + n);
    int rlen = __builtin_nontemporal_load(re + n) - e0;   // deg+1 >= 1
    int slots = (rlen + 7) & ~7;
    int iter = (slots + 31) >> 5;
    const int* cb = csr + e0;

    float a0 = 0.f, a1 = 0.f, a2 = 0.f, a3 = 0.f;
    float a4 = 0.f, a5 = 0.f, a6 = 0.f, a7 = 0.f;

    int s = __builtin_nontemporal_load(cb + g);
    if (g >= slots) s = N_NODES;               // slots can be 8..24
    uint4v u = *(const uint4v*)(pb + (s << 3) + coff);
    for (int it = 1; it < iter; ++it) {
      int off = g + (it << 5);
      int s2 = __builtin_nontemporal_load(cb + off);
      if (off >= slots) s2 = N_NODES;          // pad / next-node mask
      uint4v r = *(const uint4v*)(pb + (s2 << 3) + coff);
      acc_bf2(a0, a1, u.x); acc_bf2(a2, a3, u.y);
      acc_bf2(a4, a5, u.z); acc_bf2(a6, a7, u.w);
      u = r;
    }
    acc_bf2(a0, a1, u.x); acc_bf2(a2, a3, u.y);
    acc_bf2(a4, a5, u.z); acc_bf2(a6, a7, u.w);

    // reduce across the 32 edge-subgroups (lane bits 1..5; chunk bit 0 kept)
#define RED5(a) a += __shfl_xor(a, 2); a += __shfl_xor(a, 4); a += __shfl_xor(a, 8); \
                a += __shfl_xor(a, 16); a += __shfl_xor(a, 32);
    RED5(a0) RED5(a1) RED5(a2) RED5(a3) RED5(a4) RED5(a5) RED5(a6) RED5(a7)
#undef RED5

    float dn = __builtin_nontemporal_load(dis + n);
    if (l < 2) {                               // lane 0: feats +0..7, lane 1: +8..15
      float4v v0; v0.x = a0 * dn; v0.y = a1 * dn; v0.z = a2 * dn; v0.w = a3 * dn;
      float4v v1; v1.x = a4 * dn; v1.y = a5 * dn; v1.z = a6 * dn; v1.w = a7 * dn;
      float4v* ap = (float4v*)(agg + (size_t)n * 64 + plane * 16 + (l << 3));
      __builtin_nontemporal_store(v0, ap);
      __builtin_nontemporal_store(v1, ap + 1);
    }
  }
}

// ---------------- final: t = relu(b2 + agg.W2); out = t.Wf + bf ----------
// W2 column l lives in 64 VGPRs per lane, loaded ONCE per wave. agg rows are
// read coalesced (lane l -> feat l); a[j] broadcast via v_readlane with
// compile-time lane index -> single-SGPR-operand FMAs. 4 partial sums break
// the fmac dependency chain.

__global__ void __launch_bounds__(256)
k_final(const float* __restrict__ agg, const float* __restrict__ W2,
        const float* __restrict__ b2, const float* __restrict__ Wf,
        const float* __restrict__ bf, float* __restrict__ out) {
  int l = threadIdx.x & 63;
  int w = threadIdx.x >> 6;
  int wv = blockIdx.x * 4 + w;                // 0..KF_WAVES-1

  float wcol[64];
#pragma unroll
  for (int j = 0; j < 64; ++j) wcol[j] = W2[j * 64 + l];
  float bias = b2[l];
  float wf0 = Wf[l * 2 + 0];
  float wf1 = Wf[l * 2 + 1];
  float bf0 = bf[0], bf1 = bf[1];

  int n = wv;
  float av = __builtin_nontemporal_load(agg + (size_t)n * 64 + l);
  while (true) {
    int n2 = n + KF_WAVES;
    float anext = 0.f;
    if (n2 < N_NODES) anext = __builtin_nontemporal_load(agg + (size_t)n2 * 64 + l);

    unsigned ub = __float_as_uint(av);
    float t0 = bias, t1 = 0.f, t2 = 0.f, t3 = 0.f;
#pragma unroll
    for (int j = 0; j < 64; j += 4) {
      t0 = fmaf(__uint_as_float(__builtin_amdgcn_readlane(ub, j + 0)), wcol[j + 0], t0);
      t1 = fmaf(__uint_as_float(__builtin_amdgcn_readlane(ub, j + 1)), wcol[j + 1], t1);
      t2 = fmaf(__uint_as_float(__builtin_amdgcn_readlane(ub, j + 2)), wcol[j + 2], t2);
      t3 = fmaf(__uint_as_float(__builtin_amdgcn_readlane(ub, j + 3)), wcol[j + 3], t3);
    }
    float t = fmaxf((t0 + t1) + (t2 + t3), 0.f);

    float p0 = t * wf0;
    float p1 = t * wf1;
    for (int off = 32; off; off >>= 1) {
      p0 += __shfl_down(p0, off);
      p1 += __shfl_down(p1, off);
    }
    if (l == 0) {
      out[n * 2 + 0] = p0 + bf0;
      out[n * 2 + 1] = p1 + bf1;
    }
    if (n2 >= N_NODES) break;
    av = anext; n = n2;
  }
}

// ---------------- launch ----------------

extern "C" void kernel_launch(void* const* d_in, const int* in_sizes, int n_in,
                              void* d_out, int out_size, void* d_ws, size_t ws_size,
                              hipStream_t stream) {
  const float* x  = (const float*)d_in[0];
  const int*   ei = (const int*)d_in[1];     // [2, E] row-major, int32
  const float* W1 = (const float*)d_in[2];
  const float* b1 = (const float*)d_in[3];
  const float* W2 = (const float*)d_in[4];
  const float* b2 = (const float*)d_in[5];
  const float* Wf = (const float*)d_in[6];
  const float* bf = (const float*)d_in[7];
  float* out = (float*)d_out;

  const int* srcv = ei;
  const int* dstv = ei + N_EDGES;

  char* p = (char*)d_ws;
  auto take = [&](size_t bytes) { char* r = p; p += (bytes + 255) & ~(size_t)255; return r; };
  int*          gcur = (int*)take((size_t)NBUCKET * 4);
  unsigned int* eb   = (unsigned int*)take((size_t)NBUCKET * BCAP * 4 + 512);  // padded CSR
  int*          rs   = (int*)take((size_t)N_NODES * 4);
  int*          re   = (int*)take((size_t)N_NODES * 4);
  float*        dis  = (float*)take((size_t)N_NODES * 4);
  float4*       xd   = (float4*)take((size_t)(N_NODES + 1) * 16);               // + zero row
  unsigned int* h1q  = (unsigned int*)take((size_t)4 * NP1 * 8 * 4);            // 4 planes, 12.8 MB
  float*        agg  = (float*)take((size_t)N_NODES * 64 * 4);                  // 25.6 MB

  (void)hipMemsetAsync(gcur, 0, (size_t)NBUCKET * 4, stream);
  k_pass1<<<NPB, 256, 0, stream>>>(srcv, dstv, gcur, eb);
  k_part2<<<NBUCKET, 256, 0, stream>>>(eb, gcur, rs, re, dis, (const float4*)x, xd);
  const int* csr = (const int*)eb;
  k_l1<<<((N_NODES + 1) * 4 + 255) / 256, 256, 0, stream>>>(xd, dis, rs, re, csr, W1, b1, h1q);
  k_agg<<<4 * PBLK, 256, 0, stream>>>(h1q, dis, rs, re, csr, agg);
  k_final<<<KF_BLOCKS, 256, 0, stream>>>(agg, W2, b2, Wf, bf, out);
}

// Round 4
// 238.868 us; speedup vs baseline: 1.5527x; 1.5527x over previous
//
#include <hip/hip_runtime.h>
#include <hip/hip_bf16.h>

#define N_NODES 100000
#define N_EDGES 3200000
#define NB ((N_NODES + 255) / 256)   // 391
#define NBUCKET NB                   // coarse bucket = dst>>8
#define EPB 8192                     // edges per k_pass1 block
#define NPB ((N_EDGES + EPB - 1) / EPB)  // 391 blocks
#define BCAP 11264                   // per-bucket cap incl self+pad(8)+guard; mean ~9344, 20 sigma
#define KF_BLOCKS 1280               // k_final: 5120 waves = 5 waves/SIMD
#define KF_WAVES (KF_BLOCKS * 4)

// RNE float->bf16 bits (matches __float2bfloat16 for finite values)
__device__ inline unsigned f2bf(float f) {
  unsigned x = __float_as_uint(f);
  return (x + 0x7FFFu + ((x >> 16) & 1u)) >> 16;
}

// ---------------- pass 1: register-resident coarse partition ----------------
// item: bits[16:0] = src, bits[24:17] = dst & 255 (bucket = dst>>8).
// Single LDS-atomic round: per-item position packed into bits[31:25].

__global__ void __launch_bounds__(256) k_pass1(const int* __restrict__ src,
                                               const int* __restrict__ dst,
                                               int* __restrict__ gcur,
                                               unsigned int* __restrict__ eb) {
  __shared__ int hist[NBUCKET];
  __shared__ int gbase[NBUCKET];
  int tid = threadIdx.x;
  int base = blockIdx.x * EPB;
  int cnt = min(EPB, N_EDGES - base);   // multiple of 4
  int n4 = cnt >> 2;
  for (int i = tid; i < NBUCKET; i += 256) hist[i] = 0;
  __syncthreads();
  const int4* d4 = (const int4*)(dst + base);
  const int4* s4 = (const int4*)(src + base);
  unsigned mv[32];
  unsigned short mb[32];
#pragma unroll
  for (int k = 0; k < 8; ++k) {
    int i = tid + (k << 8);
    if (i < n4) {
      int4 dv = d4[i];
      int4 sv = s4[i];
      int b0 = dv.x >> 8, b1_ = dv.y >> 8, b2 = dv.z >> 8, b3 = dv.w >> 8;
      unsigned p0 = atomicAdd(&hist[b0], 1);
      unsigned p1 = atomicAdd(&hist[b1_], 1);
      unsigned p2 = atomicAdd(&hist[b2], 1);
      unsigned p3 = atomicAdd(&hist[b3], 1);
      mv[4 * k + 0] = (unsigned)sv.x | ((unsigned)(dv.x & 255) << 17) | (p0 << 25);
      mv[4 * k + 1] = (unsigned)sv.y | ((unsigned)(dv.y & 255) << 17) | (p1 << 25);
      mv[4 * k + 2] = (unsigned)sv.z | ((unsigned)(dv.z & 255) << 17) | (p2 << 25);
      mv[4 * k + 3] = (unsigned)sv.w | ((unsigned)(dv.w & 255) << 17) | (p3 << 25);
      mb[4 * k + 0] = (unsigned short)b0;
      mb[4 * k + 1] = (unsigned short)b1_;
      mb[4 * k + 2] = (unsigned short)b2;
      mb[4 * k + 3] = (unsigned short)b3;
    } else {
      mb[4 * k + 0] = 0xFFFF; mb[4 * k + 1] = 0xFFFF;
      mb[4 * k + 2] = 0xFFFF; mb[4 * k + 3] = 0xFFFF;
    }
  }
  __syncthreads();
  for (int b = tid; b < NBUCKET; b += 256) {
    int h = hist[b];
    gbase[b] = h ? atomicAdd(&gcur[b], h) : 0;   // one claim per (block,bucket)
  }
  __syncthreads();
#pragma unroll
  for (int k = 0; k < 32; ++k) {
    if (mb[k] != 0xFFFF) {
      int b = mb[k];
      unsigned v = mv[k];
      unsigned pos = (unsigned)gbase[b] + (v >> 25);
      if (pos < BCAP) eb[(size_t)b * BCAP + pos] = v & 0x01FFFFFFu;
    }
  }
}

// ---------------- pass 2: per-bucket counting sort + self-edge + pad-to-8 --------
// Node n's run: [rs[n], re[n]) real (self first), pads == N_NODES to a multiple
// of 8, 16-entry guard after the bucket total. Also emits dis, xd = x4*dis.
// Scan over 256 threads = wave shfl_up scan + 4-entry cross-wave combine
// (2 barriers instead of 16).

__global__ void __launch_bounds__(256) k_part2(unsigned int* __restrict__ eb,
                                               const int* __restrict__ gcur,
                                               int* __restrict__ rs, int* __restrict__ re,
                                               float* __restrict__ dis,
                                               const float4* __restrict__ x4,
                                               float4* __restrict__ xd) {
  __shared__ int hist[256], scn[256], cur[256];
  __shared__ int wsum[4];
  __shared__ int tot;
  __shared__ unsigned int stage[BCAP];
  int b = blockIdx.x, tid = threadIdx.x;
  int lane = tid & 63, wid = tid >> 6;
  int n0 = b << 8;
  int cnt = gcur[b];
  int base = b * BCAP;
  hist[tid] = 0; cur[tid] = 0;
  __syncthreads();
  for (int i = tid; i < cnt; i += 256)
    atomicAdd(&hist[eb[base + i] >> 17], 1);
  __syncthreads();
  int n = n0 + tid;
  int deg = hist[tid];
  int slots = (n < N_NODES) ? ((deg + 1 + 7) & ~7) : 0;
  // inclusive scan of slots: shfl_up within wave, then cross-wave offsets
  int v = slots;
#pragma unroll
  for (int off = 1; off < 64; off <<= 1) {
    int t = __shfl_up(v, off);
    if (lane >= off) v += t;
  }
  if (lane == 63) wsum[wid] = v;
  __syncthreads();
  int x = v;
#pragma unroll
  for (int w2 = 0; w2 < 3; ++w2)
    if (wid > w2) x += wsum[w2];
  int excl = x - slots;
  if (tid == 255) tot = x;
  if (n < N_NODES) {
    rs[n]  = base + excl;
    re[n]  = base + excl + deg + 1;
    float dn = rsqrtf((float)(deg + 1));
    dis[n] = dn;
    float4 xv = x4[n];
    float4 w; w.x = xv.x * dn; w.y = xv.y * dn; w.z = xv.z * dn; w.w = xv.w * dn;
    xd[n] = w;
    stage[excl] = (unsigned)n;                    // self edge
    for (int i = deg + 1; i < slots; ++i)
      stage[excl + i] = (unsigned)N_NODES;        // zero-row pads
  }
  if (b == 0 && tid == 0) xd[N_NODES] = make_float4(0.f, 0.f, 0.f, 0.f);
  scn[tid] = excl + 1;                            // in-edge start
  __syncthreads();
  for (int i = tid; i < cnt; i += 256) {
    unsigned v2 = eb[base + i];
    unsigned low = v2 >> 17;
    int lpos = scn[low] + atomicAdd(&cur[low], 1);
    stage[lpos] = v2 & 0x1FFFFu;
  }
  __syncthreads();
  int total = tot;
  for (int i = tid; i < total; i += 256)
    eb[base + i] = stage[i];     // eb is now padded CSR (src ids by dst node)
  if (tid < 16) {                // guard pads for k_agg's prefetch over-read
    int gp = total + tid;
    if (gp < BCAP) eb[base + gp] = (unsigned)N_NODES;
  }
}

// ---------------- Layer 1 fused: aggregate xd + transform + bf16 store ----------
// 4 threads per node (p = gt&3). Thread p reads csr dwords e0+4t+p (slots are
// multiples of 8; pads hit xd's zero row), shfl_xor combine, then writes
// feature slice [16p, 16p+16) of h1s[n] = bf16(relu(b1 + agg·W1) * dis[n]).

__global__ void __launch_bounds__(256) k_l1(const float4* __restrict__ xd,
                                            const float* __restrict__ dis,
                                            const int* __restrict__ rs,
                                            const int* __restrict__ re,
                                            const int* __restrict__ csr,
                                            const float* __restrict__ W1,
                                            const float* __restrict__ b1,
                                            unsigned int* __restrict__ h1o) {
  int gt = blockIdx.x * 256 + threadIdx.x;
  int nid = gt >> 2, p = gt & 3;
  if (nid > N_NODES) return;
  if (nid == N_NODES) {                       // zero row (pad target for k_agg)
    uint4 z = make_uint4(0u, 0u, 0u, 0u);
    uint4* op = (uint4*)(h1o + nid * 32 + p * 8);
    op[0] = z; op[1] = z;
    return;
  }
  int e0 = rs[nid];
  int it4 = ((re[nid] - e0 + 7) & ~7) >> 2;   // dword quads per thread-pass
  const int* cp = csr + e0 + p;
  float ax = 0.f, ay = 0.f, az = 0.f, aw = 0.f;
#pragma unroll 4
  for (int t = 0; t < it4; ++t) {
    int s = cp[t << 2];
    float4 v = xd[s];
    ax += v.x; ay += v.y; az += v.z; aw += v.w;
  }
  ax += __shfl_xor(ax, 1); ax += __shfl_xor(ax, 2);
  ay += __shfl_xor(ay, 1); ay += __shfl_xor(ay, 2);
  az += __shfl_xor(az, 1); az += __shfl_xor(az, 2);
  aw += __shfl_xor(aw, 1); aw += __shfl_xor(aw, 2);
  float dn = dis[nid];
  ax *= dn; ay *= dn; az *= dn; aw *= dn;     // agg1[nid]
  int j0 = p << 4;
  unsigned ou[8];
#pragma unroll
  for (int j2 = 0; j2 < 8; ++j2) {
    int j = j0 + j2 * 2;
    float s0 = b1[j]     + ax * W1[j]     + ay * W1[64 + j]     + az * W1[128 + j]     + aw * W1[192 + j];
    float s1 = b1[j + 1] + ax * W1[j + 1] + ay * W1[64 + j + 1] + az * W1[128 + j + 1] + aw * W1[192 + j + 1];
    unsigned u0 = f2bf(fmaxf(s0, 0.f) * dn);
    unsigned u1 = f2bf(fmaxf(s1, 0.f) * dn);
    ou[j2] = u0 | (u1 << 16);
  }
  uint4* op = (uint4*)(h1o + nid * 32 + p * 8);
  op[0] = make_uint4(ou[0], ou[1], ou[2], ou[3]);
  op[1] = make_uint4(ou[4], ou[5], ou[6], ou[7]);
}

// ---------------- Layer-2 aggregation: 4-deep pipelined gather ----------
// Wave per node. Lane l: g = l>>3 (edge subgroup 0..7), c = l&7 (uint4 chunk).
// FOUR 8-edge row blocks in flight per wave (was 2); csr read 4 blocks ahead
// (always within this node's run inside the loop; initial over-reach values
// are predicated to the zero row before address formation, raw reads stay
// in-bounds via the 16-entry guard + workspace slack).

__device__ inline void acc_bf2(float& a0, float& a1, unsigned u) {
  a0 += __uint_as_float(u << 16);
  a1 += __uint_as_float(u & 0xffff0000u);
}

__global__ void __launch_bounds__(256)
k_agg(const __hip_bfloat16* __restrict__ h1s, const float* __restrict__ dis,
      const int* __restrict__ rs, const int* __restrict__ re,
      const int* __restrict__ csr, float* __restrict__ agg) {
  int l = threadIdx.x & 63;
  int w = threadIdx.x >> 6;
  int n = blockIdx.x * 4 + w;   // grid = N/4 exactly
  int g = l >> 3;
  int c = l & 7;

  const unsigned int* h32 = (const unsigned int*)h1s;
  int e0 = rs[n];
  int iter = (re[n] - e0 + 7) >> 3;           // padded 8-blocks, >= 1
  const int* cb = csr + e0 + g;
  int coff = c << 2;                          // dword offset of feature chunk

  float a0 = 0.f, a1 = 0.f, a2 = 0.f, a3 = 0.f;
  float a4 = 0.f, a5 = 0.f, a6 = 0.f, a7 = 0.f;

  // 4-deep prologue: blocks 0..3 (predicated to zero row when beyond run)
  int sA = cb[0];                             // block 0: self first, always real
  int sB = (iter > 1) ? cb[8]  : N_NODES;
  int sC = (iter > 2) ? cb[16] : N_NODES;
  int sD = (iter > 3) ? cb[24] : N_NODES;
  uint4 uA = *(const uint4*)(h32 + (sA << 5) + coff);
  uint4 uB = *(const uint4*)(h32 + (sB << 5) + coff);
  uint4 uC = *(const uint4*)(h32 + (sC << 5) + coff);
  uint4 uD = *(const uint4*)(h32 + (sD << 5) + coff);

  for (int it = 0; it + 4 < iter; ++it) {
    int sN = cb[(it + 4) << 3];               // in-run: it+4 <= iter-1
    uint4 r = *(const uint4*)(h32 + (sN << 5) + coff);
    acc_bf2(a0, a1, uA.x); acc_bf2(a2, a3, uA.y);
    acc_bf2(a4, a5, uA.z); acc_bf2(a6, a7, uA.w);
    uA = uB; uB = uC; uC = uD; uD = r;
  }
  // drain: remaining 4 blocks (zero rows where predicated)
  acc_bf2(a0, a1, uA.x); acc_bf2(a2, a3, uA.y);
  acc_bf2(a4, a5, uA.z); acc_bf2(a6, a7, uA.w);
  acc_bf2(a0, a1, uB.x); acc_bf2(a2, a3, uB.y);
  acc_bf2(a4, a5, uB.z); acc_bf2(a6, a7, uB.w);
  acc_bf2(a0, a1, uC.x); acc_bf2(a2, a3, uC.y);
  acc_bf2(a4, a5, uC.z); acc_bf2(a6, a7, uC.w);
  acc_bf2(a0, a1, uD.x); acc_bf2(a2, a3, uD.y);
  acc_bf2(a4, a5, uD.z); acc_bf2(a6, a7, uD.w);

  // reduce across the 8 edge-subgroups (lane bits 3,4,5)
#define RED3(a) a += __shfl_xor(a, 8); a += __shfl_xor(a, 16); a += __shfl_xor(a, 32);
  RED3(a0) RED3(a1) RED3(a2) RED3(a3) RED3(a4) RED3(a5) RED3(a6) RED3(a7)
#undef RED3

  float dn = dis[n];
  if (l < 8) {                                // lane l == chunk c: feats 8l..8l+7
    float4 v0; v0.x = a0 * dn; v0.y = a1 * dn; v0.z = a2 * dn; v0.w = a3 * dn;
    float4 v1; v1.x = a4 * dn; v1.y = a5 * dn; v1.z = a6 * dn; v1.w = a7 * dn;
    float4* ap = (float4*)(agg + (size_t)n * 64 + (l << 3));
    ap[0] = v0; ap[1] = v1;
  }
}

// ---------------- final: t = relu(b2 + agg.W2); out = t.Wf + bf ----------
// W2 column l lives in 64 VGPRs per lane, loaded ONCE per wave. agg rows are
// read coalesced (lane l -> feat l); a[j] broadcast via v_readlane with
// compile-time lane index -> single-SGPR-operand FMAs. 4 partial sums break
// the fmac dependency chain.

__global__ void __launch_bounds__(256)
k_final(const float* __restrict__ agg, const float* __restrict__ W2,
        const float* __restrict__ b2, const float* __restrict__ Wf,
        const float* __restrict__ bf, float* __restrict__ out) {
  int l = threadIdx.x & 63;
  int w = threadIdx.x >> 6;
  int wv = blockIdx.x * 4 + w;                // 0..KF_WAVES-1

  float wcol[64];
#pragma unroll
  for (int j = 0; j < 64; ++j) wcol[j] = W2[j * 64 + l];
  float bias = b2[l];
  float wf0 = Wf[l * 2 + 0];
  float wf1 = Wf[l * 2 + 1];
  float bf0 = bf[0], bf1 = bf[1];

  int n = wv;
  float av = agg[(size_t)n * 64 + l];
  while (true) {
    int n2 = n + KF_WAVES;
    float anext = 0.f;
    if (n2 < N_NODES) anext = agg[(size_t)n2 * 64 + l];  // overlaps compute

    unsigned ub = __float_as_uint(av);
    float t0 = bias, t1 = 0.f, t2 = 0.f, t3 = 0.f;
#pragma unroll
    for (int j = 0; j < 64; j += 4) {
      t0 = fmaf(__uint_as_float(__builtin_amdgcn_readlane(ub, j + 0)), wcol[j + 0], t0);
      t1 = fmaf(__uint_as_float(__builtin_amdgcn_readlane(ub, j + 1)), wcol[j + 1], t1);
      t2 = fmaf(__uint_as_float(__builtin_amdgcn_readlane(ub, j + 2)), wcol[j + 2], t2);
      t3 = fmaf(__uint_as_float(__builtin_amdgcn_readlane(ub, j + 3)), wcol[j + 3], t3);
    }
    float t = fmaxf((t0 + t1) + (t2 + t3), 0.f);

    float p0 = t * wf0;
    float p1 = t * wf1;
    for (int off = 32; off; off >>= 1) {
      p0 += __shfl_down(p0, off);
      p1 += __shfl_down(p1, off);
    }
    if (l == 0) {
      out[n * 2 + 0] = p0 + bf0;
      out[n * 2 + 1] = p1 + bf1;
    }
    if (n2 >= N_NODES) break;
    av = anext; n = n2;
  }
}

// ---------------- launch ----------------

extern "C" void kernel_launch(void* const* d_in, const int* in_sizes, int n_in,
                              void* d_out, int out_size, void* d_ws, size_t ws_size,
                              hipStream_t stream) {
  const float* x  = (const float*)d_in[0];
  const int*   ei = (const int*)d_in[1];     // [2, E] row-major, int32
  const float* W1 = (const float*)d_in[2];
  const float* b1 = (const float*)d_in[3];
  const float* W2 = (const float*)d_in[4];
  const float* b2 = (const float*)d_in[5];
  const float* Wf = (const float*)d_in[6];
  const float* bf = (const float*)d_in[7];
  float* out = (float*)d_out;

  const int* srcv = ei;
  const int* dstv = ei + N_EDGES;

  char* p = (char*)d_ws;
  auto take = [&](size_t bytes) { char* r = p; p += (bytes + 255) & ~(size_t)255; return r; };
  int*          gcur = (int*)take((size_t)NBUCKET * 4);
  unsigned int* eb   = (unsigned int*)take((size_t)NBUCKET * BCAP * 4 + 512);  // padded CSR
  int*          rs   = (int*)take((size_t)N_NODES * 4);
  int*          re   = (int*)take((size_t)N_NODES * 4);
  float*        dis  = (float*)take((size_t)N_NODES * 4);
  float4*       xd   = (float4*)take((size_t)(N_NODES + 1) * 16);               // + zero row
  __hip_bfloat16* h1s = (__hip_bfloat16*)take((size_t)(N_NODES + 1) * 64 * 2);  // + zero row
  float*        agg  = (float*)take((size_t)N_NODES * 64 * 4);                  // 25.6 MB

  (void)hipMemsetAsync(gcur, 0, (size_t)NBUCKET * 4, stream);
  k_pass1<<<NPB, 256, 0, stream>>>(srcv, dstv, gcur, eb);
  k_part2<<<NBUCKET, 256, 0, stream>>>(eb, gcur, rs, re, dis, (const float4*)x, xd);
  const int* csr = (const int*)eb;
  k_l1<<<((N_NODES + 1) * 4 + 255) / 256, 256, 0, stream>>>(xd, dis, rs, re, csr, W1, b1, (unsigned int*)h1s);
  k_agg<<<N_NODES / 4, 256, 0, stream>>>(h1s, dis, rs, re, csr, agg);
  k_final<<<KF_BLOCKS, 256, 0, stream>>>(agg, W2, b2, Wf, bf, out);
}